// Round 11
// baseline (448.658 us; speedup 1.0000x reference)
//
#include <hip/hip_runtime.h>
#include <hip/hip_bf16.h>

#define B_  64
#define T_  30
#define E_  300
#define H_  512
#define FD_ 512
#define V_  10000
#define NR_ 32          // recurrence WGs
#define NTN_ 79         // N tiles of 128 covering V=10000
#define NTM_ 15         // M tiles of 128 covering B*T=1920
// bar[0..31]: per-WG step flags in ONE 128B line (distinct words, parallel stores;
// poll = 1 line fetch via bar[lane&31]).

typedef __attribute__((ext_vector_type(8))) unsigned short ushort8_t;
typedef __attribute__((ext_vector_type(4))) unsigned short ushort4_t;
typedef __attribute__((ext_vector_type(8))) __bf16 bf16x8;
typedef __attribute__((ext_vector_type(4))) float f32x4;

__device__ __forceinline__ float b2f(unsigned short u) {
    union { unsigned int i; float f; } v;
    v.i = ((unsigned int)u) << 16;
    return v.f;
}
__device__ __forceinline__ unsigned short f2b(float f) {
    unsigned int x = __builtin_bit_cast(unsigned int, f);
    unsigned int r = x + 0x7FFFu + ((x >> 16) & 1u);
    return (unsigned short)(r >> 16);
}
__device__ __forceinline__ f32x4 mfma16(bf16x8 a, bf16x8 b, f32x4 c) {
    return __builtin_amdgcn_mfma_f32_16x16x32_bf16(a, b, c, 0, 0, 0);
}

// ================= prep: all transposes + build_x + h0 conv + flag zero =================
struct PrepA {
    const float* tsrc[17];
    unsigned short* tdst[17];
    const int* captions;
    const float* features;
    const float* Bemb;
    unsigned short* X;          // stride 304
    const float* h0;
    unsigned short* cH0;
    int* bar;
};

__global__ __launch_bounds__(256) void prep_k(PrepA p) {
    const int blk = blockIdx.x, tid = threadIdx.x;
    __shared__ unsigned short tile[32][33];
    if (blk < 8720) {
        int z, bx, by, R, C, Rpad, ld;
        if (blk < 3072) { z = blk >> 8; int wq = blk & 255; bx = wq & 15; by = wq >> 4; R = 512; C = 512; Rpad = 512; ld = 512; }
        else if (blk < 3712) { int b2 = blk - 3072; z = 12 + b2 / 160; int wq = b2 % 160; bx = wq & 15; by = wq >> 4; R = 300; C = 512; Rpad = 320; ld = 320; }
        else { int b2 = blk - 3712; z = 16; bx = b2 % 313; by = b2 / 313; R = 512; C = 10000; Rpad = 512; ld = 512; }
        const float* __restrict__ src = p.tsrc[z];
        unsigned short* __restrict__ dst = p.tdst[z];
        const int tc = tid & 31, tr = tid >> 5;
        const int c0 = bx * 32, r0 = by * 32;
#pragma unroll
        for (int i = 0; i < 4; ++i) {
            int r = r0 + tr + i * 8, c = c0 + tc;
            unsigned short v = 0;
            if (r < R && c < C) v = f2b(src[(size_t)r * C + c]);
            tile[tr + i * 8][tc] = v;
        }
        __syncthreads();
#pragma unroll
        for (int i = 0; i < 4; ++i) {
            int c = c0 + tr + i * 8;
            int r = r0 + tc;
            if (c < C && r < Rpad) dst[(size_t)c * ld + r] = tile[tc][tr + i * 8];
        }
    } else if (blk < 11000) {
        int idx = (blk - 8720) * 256 + tid;          // over B*T*304
        if (idx < B_ * T_ * 304) {
            int r = idx / 304, e = idx - r * 304;
            int t = r >> 6, b = r & 63;
            float v = 0.f;
            if (e < E_) {
                if (t == 0) v = p.features[b * E_ + e];
                else {
                    int tok = p.captions[b * T_ + (t - 1)];
                    v = p.Bemb[(size_t)tok * E_ + e];
                }
            }
            p.X[(size_t)r * 304 + e] = f2b(v);
        }
    } else {
        int i = (blk - 11000) * 256 + tid;           // 128 blocks -> 32768 threads
        if (i < 2048) p.bar[i] = 0;                  // flag line (+ spare)
        if (i < B_ * H_) p.cH0[i] = f2b(p.h0[i]);
    }
}

// ================= chain: fused 3-stage gate preactivation =================
// 240 WGs (60 rowblocks x 4 gates), 32 rows/WG, 66.5KB LDS -> 2 WGs/CU.
struct ChainA {
    const unsigned short* X;      // [1920][304]
    const unsigned short* Vt[4];  // [512][320] (zero-padded K)
    const float* Vb[4];
    const unsigned short* St[4];  // [512][512]
    const float* Sb[4];
    const unsigned short* Ut[4];  // [512][512]
    const float* Ub[4];
    unsigned short* U[4];         // out [1920][512] bf16
};

__global__ __launch_bounds__(256) void chain_k(ChainA ca) {
    const int rb = blockIdx.x >> 2, g = blockIdx.x & 3;
    __shared__ char pool[66560];
    unsigned short* XT = (unsigned short*)pool;             // stage A in, stride 328 (20992B)
    unsigned short* R0 = (unsigned short*)pool;             // stage B out, stride 520
    unsigned short* R1 = (unsigned short*)(pool + 33280);   // stage A out, stride 520
    const int tid = threadIdx.x;
    const int wv = tid >> 6, lane = tid & 63;
    const int quad = lane >> 4, l16 = lane & 15;

    {
        const unsigned short* src = ca.X + (size_t)rb * 32 * 304;
#pragma unroll
        for (int it = 0; it < 5; ++it) {
            int id = it * 256 + tid;                        // 1280 chunks of 8
            int row = id / 40, c8 = (id % 40) * 8;
            ushort8_t v = {0, 0, 0, 0, 0, 0, 0, 0};
            if (c8 < 304) v = *(const ushort8_t*)(src + row * 304 + c8);
            *(ushort8_t*)&XT[row * 328 + c8] = v;
        }
    }
    __syncthreads();
    // ---- stage A: R1 = X @ Vt^T + Vb  (K=320 padded)
#pragma unroll
    for (int half = 0; half < 2; ++half) {
        const int cb = wv * 128 + half * 64;
        f32x4 acc[2][4] = {};
        for (int kc = 0; kc < 10; ++kc) {
            bf16x8 af[2];
#pragma unroll
            for (int mt = 0; mt < 2; ++mt)
                af[mt] = *(const bf16x8*)&XT[(mt * 16 + l16) * 328 + kc * 32 + quad * 8];
#pragma unroll
            for (int nt = 0; nt < 4; ++nt) {
                bf16x8 bf = *(const bf16x8*)(ca.Vt[g] + (size_t)(cb + nt * 16 + l16) * 320 + kc * 32 + quad * 8);
#pragma unroll
                for (int mt = 0; mt < 2; ++mt) acc[mt][nt] = mfma16(af[mt], bf, acc[mt][nt]);
            }
        }
#pragma unroll
        for (int mt = 0; mt < 2; ++mt)
#pragma unroll
            for (int nt = 0; nt < 4; ++nt) {
                int col = cb + nt * 16 + l16;
                float bv = ca.Vb[g][col];
#pragma unroll
                for (int r = 0; r < 4; ++r)
                    R1[(mt * 16 + quad * 4 + r) * 520 + col] = f2b(acc[mt][nt][r] + bv);
            }
    }
    __syncthreads();
    // ---- stage B: R0 = R1 @ St^T + Sb  (K=512)
#pragma unroll
    for (int half = 0; half < 2; ++half) {
        const int cb = wv * 128 + half * 64;
        f32x4 acc[2][4] = {};
        for (int kc = 0; kc < 16; ++kc) {
            bf16x8 af[2];
#pragma unroll
            for (int mt = 0; mt < 2; ++mt)
                af[mt] = *(const bf16x8*)&R1[(mt * 16 + l16) * 520 + kc * 32 + quad * 8];
#pragma unroll
            for (int nt = 0; nt < 4; ++nt) {
                bf16x8 bf = *(const bf16x8*)(ca.St[g] + (size_t)(cb + nt * 16 + l16) * 512 + kc * 32 + quad * 8);
#pragma unroll
                for (int mt = 0; mt < 2; ++mt) acc[mt][nt] = mfma16(af[mt], bf, acc[mt][nt]);
            }
        }
        __syncthreads();   // R0 aliases XT region; ensure pool reads done before overwrite
#pragma unroll
        for (int mt = 0; mt < 2; ++mt)
#pragma unroll
            for (int nt = 0; nt < 4; ++nt) {
                int col = cb + nt * 16 + l16;
                float bv = ca.Sb[g][col];
#pragma unroll
                for (int r = 0; r < 4; ++r)
                    R0[(mt * 16 + quad * 4 + r) * 520 + col] = f2b(acc[mt][nt][r] + bv);
            }
    }
    __syncthreads();
    // ---- stage C: global U = R0 @ Ut^T + Ub
#pragma unroll
    for (int half = 0; half < 2; ++half) {
        const int cb = wv * 128 + half * 64;
        f32x4 acc[2][4] = {};
        for (int kc = 0; kc < 16; ++kc) {
            bf16x8 af[2];
#pragma unroll
            for (int mt = 0; mt < 2; ++mt)
                af[mt] = *(const bf16x8*)&R0[(mt * 16 + l16) * 520 + kc * 32 + quad * 8];
#pragma unroll
            for (int nt = 0; nt < 4; ++nt) {
                bf16x8 bf = *(const bf16x8*)(ca.Ut[g] + (size_t)(cb + nt * 16 + l16) * 512 + kc * 32 + quad * 8);
#pragma unroll
                for (int mt = 0; mt < 2; ++mt) acc[mt][nt] = mfma16(af[mt], bf, acc[mt][nt]);
            }
        }
#pragma unroll
        for (int mt = 0; mt < 2; ++mt)
#pragma unroll
            for (int nt = 0; nt < 4; ++nt) {
                int col = cb + nt * 16 + l16;
                float bv = ca.Ub[g][col];
#pragma unroll
                for (int r = 0; r < 4; ++r)
                    ca.U[g][(size_t)(rb * 32 + mt * 16 + quad * 4 + r) * 512 + col] =
                        f2b(acc[mt][nt][r] + bv);
            }
    }
}

// ================= rec: recurrence ONLY (32 WGs, nothing else on GPU) =================
struct RecA {
    const unsigned short* h0c;    // [B][H] bf16
    const unsigned short* Wt[4];  // [512][512]
    const float* Wb[4];
    const unsigned short* U[4];   // [1920][512] bf16
    const float* c0;              // f32
    unsigned short* Hall;         // [1920][512] bf16
    int* bar;                     // [0..31] flags, one line
};

__global__ __launch_bounds__(256, 1) void rec_k(RecA a) {
    __shared__ char pool[83712];
    const int tid = threadIdx.x;
    const int lane = tid & 63;
    const int quad = lane >> 4, l16 = lane & 15;
    unsigned short* hs = (unsigned short*)pool;       // 64 x 520
    float* xch = (float*)(pool + 66560);              // [4][16*65]
    const int j = blockIdx.x;
    const int g = tid >> 6;
    bf16x8 afrag[16];
    {
        const unsigned short* wt = a.Wt[g] + (size_t)(j * 16 + l16) * H_ + quad * 8;
#pragma unroll
        for (int kc = 0; kc < 16; ++kc) afrag[kc] = *(const bf16x8*)(wt + kc * 32);
    }
    const int eb = tid >> 2;
    const int ehc = (tid & 3) * 4;
    const int hcg = j * 16 + ehc;
    f32x4 wb[4];
#pragma unroll
    for (int q = 0; q < 4; ++q) wb[q] = *(const f32x4*)(a.Wb[q] + hcg);
    f32x4 c = *(const f32x4*)(a.c0 + (size_t)eb * H_ + hcg);

    for (int t = 0; t < T_; ++t) {
        // prefetch U for this step (h-independent)
        ushort4_t u[4];
#pragma unroll
        for (int q = 0; q < 4; ++q)
            u[q] = *(const ushort4_t*)(a.U[q] + ((size_t)t * B_ + eb) * H_ + hcg);
        // stage full h into LDS
        const unsigned short* hp = t ? (a.Hall + (size_t)(t - 1) * B_ * H_) : a.h0c;
#pragma unroll
        for (int it = 0; it < 16; ++it) {
            int id = it * 256 + tid;
            int row = id >> 6, c8 = (id & 63) * 8;
            ushort8_t v = *(const ushort8_t*)(hp + row * H_ + c8);
            *(ushort8_t*)&hs[row * 520 + c8] = v;
        }
        __syncthreads();
        f32x4 acc[4] = {{0.f,0.f,0.f,0.f},{0.f,0.f,0.f,0.f},{0.f,0.f,0.f,0.f},{0.f,0.f,0.f,0.f}};
#pragma unroll
        for (int kc = 0; kc < 16; ++kc) {
#pragma unroll
            for (int nt = 0; nt < 4; ++nt) {
                bf16x8 bfr = *(const bf16x8*)&hs[(nt * 16 + l16) * 520 + kc * 32 + quad * 8];
                acc[nt] = mfma16(afrag[kc], bfr, acc[nt]);
            }
        }
#pragma unroll
        for (int nt = 0; nt < 4; ++nt)
#pragma unroll
            for (int r = 0; r < 4; ++r)
                xch[g * 1040 + (quad * 4 + r) * 65 + nt * 16 + l16] = acc[nt][r];
        __syncthreads();
        ushort4_t hnew;
#pragma unroll
        for (int r = 0; r < 4; ++r) {
            float pi = xch[0 * 1040 + (ehc + r) * 65 + eb] + b2f(u[0][r]) + wb[0][r];
            float pf = xch[1 * 1040 + (ehc + r) * 65 + eb] + b2f(u[1][r]) + wb[1][r];
            float po = xch[2 * 1040 + (ehc + r) * 65 + eb] + b2f(u[2][r]) + wb[2][r];
            float pc = xch[3 * 1040 + (ehc + r) * 65 + eb] + b2f(u[3][r]) + wb[3][r];
            float it = 1.f / (1.f + __expf(-pi));
            float ft = 1.f / (1.f + __expf(-pf));
            float ot = 1.f / (1.f + __expf(-po));
            float ct = tanhf(pc);
            float cn = ft * c[r] + it * ct;
            c[r] = cn;
            hnew[r] = f2b(ot * cn);
        }
        {
            union { ushort4_t s4; unsigned long long q; } hu;
            hu.s4 = hnew;
            __hip_atomic_store((unsigned long long*)(a.Hall + ((size_t)t * B_ + eb) * H_ + hcg),
                               hu.q, __ATOMIC_RELAXED, __HIP_MEMORY_SCOPE_AGENT);
        }
        asm volatile("s_waitcnt vmcnt(0)" ::: "memory");
        __syncthreads();   // all waves' h stores drained
        if (t + 1 < T_) {
            // single-line barrier: parallel per-WG word stores, one-line poll
            if (tid == 0)
                __hip_atomic_store(&a.bar[j], t + 1, __ATOMIC_RELAXED, __HIP_MEMORY_SCOPE_AGENT);
            if (g == 0) {
                bool done;
                do {
                    int v = __hip_atomic_load(&a.bar[lane & 31], __ATOMIC_RELAXED, __HIP_MEMORY_SCOPE_AGENT);
                    done = __all(v >= t + 1);
                    if (!done) __builtin_amdgcn_s_sleep(1);
                } while (!done);
            }
            __syncthreads();
        }
    }
}

// ================= proj: clean ungated GEMM (B*T=1920)x(V=10000), K=512 =================
// out row permutation applied in epilogue: A row m = t*B+b  ->  out row b*T+t.
struct ProjA {
    const unsigned short* Hall;   // [1920][512] bf16
    const unsigned short* Ct;     // [10000][512] bf16
    const float* Cb;
    float* out;                   // [B][T][V] f32
};

__global__ __launch_bounds__(256) void proj_k(ProjA a) {
    __shared__ unsigned short As[128 * 72];   // 18432 B
    __shared__ unsigned short Bs[128 * 72];   // 18432 B
    const int tid = threadIdx.x;
    const int lane = tid & 63, wv = tid >> 6;
    const int quad = lane >> 4, l16 = lane & 15;
    const int mq = (wv & 1) * 64, nq = (wv >> 1) * 64;
    const int m0 = ((int)blockIdx.x / NTN_) * 128;
    const int n0 = ((int)blockIdx.x % NTN_) * 128;
    f32x4 acc[4][4] = {};
    for (int k0 = 0; k0 < H_; k0 += 64) {
        {
            int id = tid;
#pragma unroll
            for (int it = 0; it < 4; ++it, id += 256) {
                int row = id >> 3, c8 = (id & 7) * 8;
                *(ushort8_t*)&As[row * 72 + c8] =
                    *(const ushort8_t*)(a.Hall + (size_t)(m0 + row) * H_ + k0 + c8);
            }
            int id2 = tid;
#pragma unroll
            for (int it = 0; it < 4; ++it, id2 += 256) {
                int row = id2 >> 3, c8 = (id2 & 7) * 8;
                int gn = n0 + row;
                ushort8_t v = {0, 0, 0, 0, 0, 0, 0, 0};
                if (gn < V_) v = *(const ushort8_t*)(a.Ct + (size_t)gn * H_ + k0 + c8);
                *(ushort8_t*)&Bs[row * 72 + c8] = v;
            }
        }
        __syncthreads();
#pragma unroll
        for (int kk = 0; kk < 2; ++kk) {
            bf16x8 af[4], bf[4];
#pragma unroll
            for (int mt = 0; mt < 4; ++mt)
                af[mt] = *(const bf16x8*)&As[(mq + mt * 16 + l16) * 72 + kk * 32 + quad * 8];
#pragma unroll
            for (int nt = 0; nt < 4; ++nt)
                bf[nt] = *(const bf16x8*)&Bs[(nq + nt * 16 + l16) * 72 + kk * 32 + quad * 8];
#pragma unroll
            for (int mt = 0; mt < 4; ++mt)
#pragma unroll
                for (int nt = 0; nt < 4; ++nt)
                    acc[mt][nt] = mfma16(af[mt], bf[nt], acc[mt][nt]);
        }
        __syncthreads();
    }
#pragma unroll
    for (int mt = 0; mt < 4; ++mt)
#pragma unroll
        for (int nt = 0; nt < 4; ++nt) {
            int col = n0 + nq + nt * 16 + l16;
            if (col >= V_) continue;
            float bv = a.Cb[col];
#pragma unroll
            for (int r = 0; r < 4; ++r) {
                int m = m0 + mq + mt * 16 + quad * 4 + r;
                int t = m >> 6, b = m & 63;
                a.out[(size_t)(b * T_ + t) * V_ + col] = acc[mt][nt][r] + bv;
            }
        }
}

extern "C" void kernel_launch(void* const* d_in, const int* in_sizes, int n_in,
                              void* d_out, int out_size, void* d_ws, size_t ws_size,
                              hipStream_t stream) {
    (void)in_sizes; (void)n_in; (void)out_size; (void)ws_size;
    const int* captions = (const int*)d_in[0];
    const float* features = (const float*)d_in[1];
    const float* h0 = (const float*)d_in[2];
    const float* c0 = (const float*)d_in[3];
    const float* Bemb = (const float*)d_in[4];
    const float *iVW[4], *iVb[4], *iSW[4], *iSb[4], *iUW[4], *iUb[4], *iWW[4], *iWb[4];
    for (int g = 0; g < 4; ++g) {
        const int base = 5 + 8 * g;
        iVW[g] = (const float*)d_in[base + 0];
        iVb[g] = (const float*)d_in[base + 1];
        iSW[g] = (const float*)d_in[base + 2];
        iSb[g] = (const float*)d_in[base + 3];
        iUW[g] = (const float*)d_in[base + 4];
        iUb[g] = (const float*)d_in[base + 5];
        iWW[g] = (const float*)d_in[base + 6];
        iWb[g] = (const float*)d_in[base + 7];
    }
    const float* CW = (const float*)d_in[37];
    const float* Cb = (const float*)d_in[38];

    char* w = (char*)d_ws;
    auto alloc = [&](size_t bytes) -> void* {
        void* p = (void*)w;
        w += (bytes + 255) & ~(size_t)255;
        return p;
    };
    int* dbar = (int*)alloc(8192);   // flag line (words 0..31)
    unsigned short* cH0 = (unsigned short*)alloc((size_t)B_ * H_ * 2);
    unsigned short *wVt[4], *wSt[4], *wUt[4], *wWt[4];
    for (int g = 0; g < 4; ++g) wVt[g] = (unsigned short*)alloc((size_t)FD_ * 320 * 2);
    for (int g = 0; g < 4; ++g) wSt[g] = (unsigned short*)alloc((size_t)FD_ * FD_ * 2);
    for (int g = 0; g < 4; ++g) wUt[g] = (unsigned short*)alloc((size_t)H_ * FD_ * 2);
    for (int g = 0; g < 4; ++g) wWt[g] = (unsigned short*)alloc((size_t)H_ * H_ * 2);
    unsigned short* wCt = (unsigned short*)alloc((size_t)V_ * H_ * 2);
    unsigned short* wX = (unsigned short*)alloc((size_t)B_ * T_ * 304 * 2);
    unsigned short* bufA[4];
    for (int g = 0; g < 4; ++g) bufA[g] = (unsigned short*)alloc((size_t)B_ * T_ * FD_ * 2);
    unsigned short* Hall = (unsigned short*)alloc((size_t)B_ * T_ * H_ * 2);

    // ---- dispatch 1: prep (transposes + build_x + h0 + flags)
    {
        PrepA p{};
        for (int g = 0; g < 4; ++g) {
            p.tsrc[g * 3 + 0] = iSW[g]; p.tdst[g * 3 + 0] = wSt[g];
            p.tsrc[g * 3 + 1] = iUW[g]; p.tdst[g * 3 + 1] = wUt[g];
            p.tsrc[g * 3 + 2] = iWW[g]; p.tdst[g * 3 + 2] = wWt[g];
            p.tsrc[12 + g] = iVW[g];    p.tdst[12 + g] = wVt[g];
        }
        p.tsrc[16] = CW; p.tdst[16] = wCt;
        p.captions = captions; p.features = features; p.Bemb = Bemb; p.X = wX;
        p.h0 = h0; p.cH0 = cH0; p.bar = dbar;
        prep_k<<<dim3(11128), 256, 0, stream>>>(p);
    }

    // ---- dispatch 2: fused 3-stage chain (240 WGs, 2/CU)
    {
        ChainA ca{};
        ca.X = wX;
        for (int g = 0; g < 4; ++g) {
            ca.Vt[g] = wVt[g]; ca.Vb[g] = iVb[g];
            ca.St[g] = wSt[g]; ca.Sb[g] = iSb[g];
            ca.Ut[g] = wUt[g]; ca.Ub[g] = iUb[g];
            ca.U[g] = bufA[g];
        }
        chain_k<<<dim3(240), 256, 0, stream>>>(ca);
    }

    // ---- dispatch 3: recurrence alone (32 WGs, zero interference)
    {
        RecA ra{};
        ra.h0c = cH0;
        for (int g = 0; g < 4; ++g) {
            ra.Wt[g] = wWt[g]; ra.Wb[g] = iWb[g]; ra.U[g] = bufA[g];
        }
        ra.c0 = c0;
        ra.Hall = Hall;
        ra.bar = dbar;
        rec_k<<<dim3(NR_), 256, 0, stream>>>(ra);
    }

    // ---- dispatch 4: projection as clean ungated GEMM
    {
        ProjA pa{};
        pa.Hall = Hall;
        pa.Ct = wCt;
        pa.Cb = Cb;
        pa.out = (float*)d_out;
        proj_k<<<dim3(NTM_ * NTN_), 256, 0, stream>>>(pa);
    }
}

// Round 18
// 434.450 us; speedup vs baseline: 1.0327x; 1.0327x over previous
//
#include <hip/hip_runtime.h>
#include <hip/hip_bf16.h>

#define B_  64
#define T_  30
#define E_  300
#define H_  512
#define FD_ 512
#define V_  10000
#define NR_ 32          // recurrence WGs
#define NPW_ 224        // projection WGs
#define NTN_ 79         // N tiles of 128 covering V=10000
#define NTG_ 8          // t-groups of 4 covering T=30 (last group has 2)
#define AGGF_ 1056      // aggregated epoch flag: byte 4224, own cache line
#define PCNT_ 1088      // CW-transpose completion counter: byte 4352, own cache line
#define CWT_  5008      // CW transpose tiles: 313 x 16
// bar[0..31]: per-WG rec step flags in ONE 128B line.

typedef __attribute__((ext_vector_type(8))) unsigned short ushort8_t;
typedef __attribute__((ext_vector_type(4))) unsigned short ushort4_t;
typedef __attribute__((ext_vector_type(8))) __bf16 bf16x8;
typedef __attribute__((ext_vector_type(4))) float f32x4;

__device__ __forceinline__ float b2f(unsigned short u) {
    union { unsigned int i; float f; } v;
    v.i = ((unsigned int)u) << 16;
    return v.f;
}
__device__ __forceinline__ unsigned short f2b(float f) {
    unsigned int x = __builtin_bit_cast(unsigned int, f);
    unsigned int r = x + 0x7FFFu + ((x >> 16) & 1u);
    return (unsigned short)(r >> 16);
}
__device__ __forceinline__ f32x4 mfma16(bf16x8 a, bf16x8 b, f32x4 c) {
    return __builtin_amdgcn_mfma_f32_16x16x32_bf16(a, b, c, 0, 0, 0);
}

// ================= prep: V/S/U/W transposes + h0 conv + flag zero (3840 blocks) =================
struct PrepA {
    const float* tsrc[16];
    unsigned short* tdst[16];
    const float* h0;
    unsigned short* cH0;
    int* bar;
};

__global__ __launch_bounds__(256) void prep_k(PrepA p) {
    const int blk = blockIdx.x, tid = threadIdx.x;
    __shared__ unsigned short tile[32][33];
    if (blk < 3712) {
        int z, bx, by, R, C, Rpad, ld;
        if (blk < 3072) { z = blk >> 8; int wq = blk & 255; bx = wq & 15; by = wq >> 4; R = 512; C = 512; Rpad = 512; ld = 512; }
        else { int b2 = blk - 3072; z = 12 + b2 / 160; int wq = b2 % 160; bx = wq & 15; by = wq >> 4; R = 300; C = 512; Rpad = 320; ld = 320; }
        const float* __restrict__ src = p.tsrc[z];
        unsigned short* __restrict__ dst = p.tdst[z];
        const int tc = tid & 31, tr = tid >> 5;
        const int c0 = bx * 32, r0 = by * 32;
#pragma unroll
        for (int i = 0; i < 4; ++i) {
            int r = r0 + tr + i * 8, c = c0 + tc;
            unsigned short v = 0;
            if (r < R && c < C) v = f2b(src[(size_t)r * C + c]);
            tile[tr + i * 8][tc] = v;
        }
        __syncthreads();
#pragma unroll
        for (int i = 0; i < 4; ++i) {
            int c = c0 + tr + i * 8;
            int r = r0 + tc;
            if (c < C && r < Rpad) dst[(size_t)c * ld + r] = tile[tc][tr + i * 8];
        }
    } else {
        int i = (blk - 3712) * 256 + tid;            // 128 blocks -> 32768 threads
        if (i < 2048) p.bar[i] = 0;                  // flag line + AGGF + PCNT lines
        if (i < B_ * H_) p.cH0[i] = f2b(p.h0[i]);
    }
}

// ================= chain: fused embed + 3-stage gate preactivation =================
// 240 WGs (60 rowblocks x 4 gates), 32 rows/WG, 66.5KB LDS -> 2 WGs/CU.
// X is built on the fly: row gr=(t,b) -> features (t==0) or Bemb[captions[b][t-1]].
struct ChainA {
    const int* captions;
    const float* features;
    const float* Bemb;
    const unsigned short* Vt[4];  // [512][320] (zero-padded K)
    const float* Vb[4];
    const unsigned short* St[4];  // [512][512]
    const float* Sb[4];
    const unsigned short* Ut[4];  // [512][512]
    const float* Ub[4];
    unsigned short* U[4];         // out [1920][512] bf16
};

__global__ __launch_bounds__(256) void chain_k(ChainA ca) {
    const int rb = blockIdx.x >> 2, g = blockIdx.x & 3;
    __shared__ char pool[66560];
    unsigned short* XT = (unsigned short*)pool;             // stage A in, stride 328
    unsigned short* R0 = (unsigned short*)pool;             // stage B out, stride 520
    unsigned short* R1 = (unsigned short*)(pool + 33280);   // stage A out, stride 520
    const int tid = threadIdx.x;
    const int wv = tid >> 6, lane = tid & 63;
    const int quad = lane >> 4, l16 = lane & 15;

    {
        const int rows0 = rb * 32;
#pragma unroll
        for (int it = 0; it < 5; ++it) {
            int id = it * 256 + tid;                        // 1280 chunks of 8
            int row = id / 40, c8 = (id % 40) * 8;
            int gr = rows0 + row;
            int t = gr >> 6, b = gr & 63;
            ushort8_t v = {0, 0, 0, 0, 0, 0, 0, 0};
            if (c8 < 304) {
                const float* src;
                if (t == 0) src = ca.features + (size_t)b * E_;
                else {
                    int tok = ca.captions[b * T_ + (t - 1)];
                    src = ca.Bemb + (size_t)tok * E_;
                }
                if (c8 + 8 <= E_) {
                    f32x4 aa = *(const f32x4*)(src + c8);
                    f32x4 bb = *(const f32x4*)(src + c8 + 4);
                    v[0] = f2b(aa[0]); v[1] = f2b(aa[1]); v[2] = f2b(aa[2]); v[3] = f2b(aa[3]);
                    v[4] = f2b(bb[0]); v[5] = f2b(bb[1]); v[6] = f2b(bb[2]); v[7] = f2b(bb[3]);
                } else {
#pragma unroll
                    for (int i2 = 0; i2 < 8; ++i2) {
                        int e = c8 + i2;
                        if (e < E_) v[i2] = f2b(src[e]);
                    }
                }
            }
            *(ushort8_t*)&XT[row * 328 + c8] = v;
        }
    }
    __syncthreads();
    // ---- stage A: R1 = X @ Vt^T + Vb  (K=320 padded)
#pragma unroll
    for (int half = 0; half < 2; ++half) {
        const int cb = wv * 128 + half * 64;
        f32x4 acc[2][4] = {};
        for (int kc = 0; kc < 10; ++kc) {
            bf16x8 af[2];
#pragma unroll
            for (int mt = 0; mt < 2; ++mt)
                af[mt] = *(const bf16x8*)&XT[(mt * 16 + l16) * 328 + kc * 32 + quad * 8];
#pragma unroll
            for (int nt = 0; nt < 4; ++nt) {
                bf16x8 bf = *(const bf16x8*)(ca.Vt[g] + (size_t)(cb + nt * 16 + l16) * 320 + kc * 32 + quad * 8);
#pragma unroll
                for (int mt = 0; mt < 2; ++mt) acc[mt][nt] = mfma16(af[mt], bf, acc[mt][nt]);
            }
        }
#pragma unroll
        for (int mt = 0; mt < 2; ++mt)
#pragma unroll
            for (int nt = 0; nt < 4; ++nt) {
                int col = cb + nt * 16 + l16;
                float bv = ca.Vb[g][col];
#pragma unroll
                for (int r = 0; r < 4; ++r)
                    R1[(mt * 16 + quad * 4 + r) * 520 + col] = f2b(acc[mt][nt][r] + bv);
            }
    }
    __syncthreads();
    // ---- stage B: R0 = R1 @ St^T + Sb  (K=512)
#pragma unroll
    for (int half = 0; half < 2; ++half) {
        const int cb = wv * 128 + half * 64;
        f32x4 acc[2][4] = {};
        for (int kc = 0; kc < 16; ++kc) {
            bf16x8 af[2];
#pragma unroll
            for (int mt = 0; mt < 2; ++mt)
                af[mt] = *(const bf16x8*)&R1[(mt * 16 + l16) * 520 + kc * 32 + quad * 8];
#pragma unroll
            for (int nt = 0; nt < 4; ++nt) {
                bf16x8 bf = *(const bf16x8*)(ca.St[g] + (size_t)(cb + nt * 16 + l16) * 512 + kc * 32 + quad * 8);
#pragma unroll
                for (int mt = 0; mt < 2; ++mt) acc[mt][nt] = mfma16(af[mt], bf, acc[mt][nt]);
            }
        }
        __syncthreads();   // R0 aliases XT region; ensure pool reads done before overwrite
#pragma unroll
        for (int mt = 0; mt < 2; ++mt)
#pragma unroll
            for (int nt = 0; nt < 4; ++nt) {
                int col = cb + nt * 16 + l16;
                float bv = ca.Sb[g][col];
#pragma unroll
                for (int r = 0; r < 4; ++r)
                    R0[(mt * 16 + quad * 4 + r) * 520 + col] = f2b(acc[mt][nt][r] + bv);
            }
    }
    __syncthreads();
    // ---- stage C: global U = R0 @ Ut^T + Ub
#pragma unroll
    for (int half = 0; half < 2; ++half) {
        const int cb = wv * 128 + half * 64;
        f32x4 acc[2][4] = {};
        for (int kc = 0; kc < 16; ++kc) {
            bf16x8 af[2];
#pragma unroll
            for (int mt = 0; mt < 2; ++mt)
                af[mt] = *(const bf16x8*)&R0[(mt * 16 + l16) * 520 + kc * 32 + quad * 8];
#pragma unroll
            for (int nt = 0; nt < 4; ++nt) {
                bf16x8 bf = *(const bf16x8*)(ca.Ut[g] + (size_t)(cb + nt * 16 + l16) * 512 + kc * 32 + quad * 8);
#pragma unroll
                for (int mt = 0; mt < 2; ++mt) acc[mt][nt] = mfma16(af[mt], bf, acc[mt][nt]);
            }
        }
#pragma unroll
        for (int mt = 0; mt < 2; ++mt)
#pragma unroll
            for (int nt = 0; nt < 4; ++nt) {
                int col = cb + nt * 16 + l16;
                float bv = ca.Ub[g][col];
#pragma unroll
                for (int r = 0; r < 4; ++r)
                    ca.U[g][(size_t)(rb * 32 + mt * 16 + quad * 4 + r) * 512 + col] =
                        f2b(acc[mt][nt][r] + bv);
            }
    }
}

// ================= mega: recurrence (32 WGs) + CW-transpose + gated projection (224 WGs) =====
struct MegaA {
    const unsigned short* h0c;    // [B][H] bf16
    const unsigned short* Wt[4];  // [512][512]
    const float* Wb[4];
    const unsigned short* U[4];   // [1920][512] bf16
    const float* c0;              // f32
    unsigned short* Hall;         // [1920][512] bf16
    int* bar;                     // [0..31] flags, [AGGF_] epoch, [PCNT_] transpose ctr
    const float* CW;              // [512][10000] f32 (source)
    unsigned short* Ct;           // [10000][512] bf16 (built by proj WGs)
    const float* Cb;
    float* out;                   // [B][T][V] f32
};

__global__ __launch_bounds__(256, 1) void mega_k(MegaA a) {
    __shared__ char pool[83712];
    const int tid = threadIdx.x;
    const int lane = tid & 63;
    const int quad = lane >> 4, l16 = lane & 15;

    if (blockIdx.x < NR_) {
        // -------- recurrence WG: owns h-cols [j*16, j*16+16), wave g = gate
        unsigned short* hs = (unsigned short*)pool;       // 64 x 520
        float* xch = (float*)(pool + 66560);              // [4][16*65]
        const int j = blockIdx.x;
        const int g = tid >> 6;
        bf16x8 afrag[16];
        {
            const unsigned short* wt = a.Wt[g] + (size_t)(j * 16 + l16) * H_ + quad * 8;
#pragma unroll
            for (int kc = 0; kc < 16; ++kc) afrag[kc] = *(const bf16x8*)(wt + kc * 32);
        }
        const int eb = tid >> 2;
        const int ehc = (tid & 3) * 4;
        const int hcg = j * 16 + ehc;
        f32x4 wb[4];
#pragma unroll
        for (int q = 0; q < 4; ++q) wb[q] = *(const f32x4*)(a.Wb[q] + hcg);
        f32x4 c = *(const f32x4*)(a.c0 + (size_t)eb * H_ + hcg);

        for (int t = 0; t < T_; ++t) {
            ushort4_t u[4];
#pragma unroll
            for (int q = 0; q < 4; ++q)
                u[q] = *(const ushort4_t*)(a.U[q] + ((size_t)t * B_ + eb) * H_ + hcg);
            const unsigned short* hp = t ? (a.Hall + (size_t)(t - 1) * B_ * H_) : a.h0c;
#pragma unroll
            for (int it = 0; it < 16; ++it) {
                int id = it * 256 + tid;
                int row = id >> 6, c8 = (id & 63) * 8;
                ushort8_t v = *(const ushort8_t*)(hp + row * H_ + c8);
                *(ushort8_t*)&hs[row * 520 + c8] = v;
            }
            __syncthreads();
            f32x4 acc[4] = {{0.f,0.f,0.f,0.f},{0.f,0.f,0.f,0.f},{0.f,0.f,0.f,0.f},{0.f,0.f,0.f,0.f}};
#pragma unroll
            for (int kc = 0; kc < 16; ++kc) {
#pragma unroll
                for (int nt = 0; nt < 4; ++nt) {
                    bf16x8 bfr = *(const bf16x8*)&hs[(nt * 16 + l16) * 520 + kc * 32 + quad * 8];
                    acc[nt] = mfma16(afrag[kc], bfr, acc[nt]);
                }
            }
#pragma unroll
            for (int nt = 0; nt < 4; ++nt)
#pragma unroll
                for (int r = 0; r < 4; ++r)
                    xch[g * 1040 + (quad * 4 + r) * 65 + nt * 16 + l16] = acc[nt][r];
            __syncthreads();
            ushort4_t hnew;
#pragma unroll
            for (int r = 0; r < 4; ++r) {
                float pi = xch[0 * 1040 + (ehc + r) * 65 + eb] + b2f(u[0][r]) + wb[0][r];
                float pf = xch[1 * 1040 + (ehc + r) * 65 + eb] + b2f(u[1][r]) + wb[1][r];
                float po = xch[2 * 1040 + (ehc + r) * 65 + eb] + b2f(u[2][r]) + wb[2][r];
                float pc = xch[3 * 1040 + (ehc + r) * 65 + eb] + b2f(u[3][r]) + wb[3][r];
                float it = 1.f / (1.f + __expf(-pi));
                float ft = 1.f / (1.f + __expf(-pf));
                float ot = 1.f / (1.f + __expf(-po));
                float ct = tanhf(pc);
                float cn = ft * c[r] + it * ct;
                c[r] = cn;
                hnew[r] = f2b(ot * cn);
            }
            {
                union { ushort4_t s4; unsigned long long q; } hu;
                hu.s4 = hnew;
                __hip_atomic_store((unsigned long long*)(a.Hall + ((size_t)t * B_ + eb) * H_ + hcg),
                                   hu.q, __ATOMIC_RELAXED, __HIP_MEMORY_SCOPE_AGENT);
            }
            asm volatile("s_waitcnt vmcnt(0)" ::: "memory");
            __syncthreads();   // all waves' h stores drained
            if (tid == 0)
                __hip_atomic_store(&a.bar[j], t + 1, __ATOMIC_RELAXED, __HIP_MEMORY_SCOPE_AGENT);
            if (t + 1 < T_ || j == 0) {
                if (g == 0) {
                    bool done;
                    do {
                        int v = __hip_atomic_load(&a.bar[lane & 31], __ATOMIC_RELAXED, __HIP_MEMORY_SCOPE_AGENT);
                        done = __all(v >= t + 1);
                        if (!done) __builtin_amdgcn_s_sleep(1);
                    } while (!done);
                    if (j == 0 && lane == 0)
                        __hip_atomic_store(&a.bar[AGGF_], t + 1, __ATOMIC_RELAXED, __HIP_MEMORY_SCOPE_AGENT);
                }
                if (t + 1 < T_) __syncthreads();
            }
        }
    } else {
        const int w = (int)blockIdx.x - NR_;
        // -------- phase 0: cooperative CW transpose (fills wCt) during rec's early steps.
        // Agent-scope 8B stores for cross-XCD visibility (same recipe as Hall).
        {
            unsigned short (*tile)[33] = (unsigned short(*)[33])pool;   // 32x33 ushort
            for (int tb2 = w; tb2 < CWT_; tb2 += NPW_) {
                const int bx = tb2 % 313, by = tb2 / 313;
                const int c0 = bx * 32, r0 = by * 32;
                const int tc = tid & 31, tr = tid >> 5;
                __syncthreads();   // protect tile reuse across iterations
#pragma unroll
                for (int i = 0; i < 4; ++i) {
                    int r = r0 + tr + i * 8, c = c0 + tc;
                    unsigned short v = 0;
                    if (c < V_) v = f2b(a.CW[(size_t)r * V_ + c]);
                    tile[tr + i * 8][tc] = v;
                }
                __syncthreads();
                {
                    int cl = tid >> 3, rch = (tid & 7) * 4;
                    int c = c0 + cl;
                    if (c < V_) {
                        union { unsigned short s[4]; unsigned long long q; } pk;
#pragma unroll
                        for (int k = 0; k < 4; ++k) pk.s[k] = tile[rch + k][cl];
                        __hip_atomic_store((unsigned long long*)(a.Ct + (size_t)c * H_ + r0 + rch),
                                           pk.q, __ATOMIC_RELAXED, __HIP_MEMORY_SCOPE_AGENT);
                    }
                }
            }
            asm volatile("s_waitcnt vmcnt(0)" ::: "memory");
            __syncthreads();
            if (tid == 0)
                __hip_atomic_fetch_add(&a.bar[PCNT_], 1, __ATOMIC_RELAXED, __HIP_MEMORY_SCOPE_AGENT);
            if (tid < 64) {
                while (__hip_atomic_load(&a.bar[PCNT_], __ATOMIC_RELAXED, __HIP_MEMORY_SCOPE_AGENT) < NPW_)
                    __builtin_amdgcn_s_sleep(4);
            }
            __syncthreads();
        }
        // -------- phase 1: t-group batched projection (G=4 t's share one Ct tile load)
        unsigned short* As = (unsigned short*)pool;              // [4][64][72]
        unsigned short* Bs = (unsigned short*)(pool + 36864);    // [128][72]
        const int wv = tid >> 6;
        const int mw = (wv & 1) * 32, nw = (wv >> 1) * 64;
        const int NJ = NTG_ * NTN_;                              // 632 jobs
        int hiF = 0;
        for (int q = w; q < NJ; q += NPW_) {
            const int tg = q / NTN_, n0 = (q % NTN_) * 128;
            const int tb = tg * 4;
            const int need = (tb + 4 < T_) ? tb + 4 : T_;
            if (need > hiF) {
                if (tid < 64) {
                    while (__hip_atomic_load(&a.bar[AGGF_], __ATOMIC_RELAXED, __HIP_MEMORY_SCOPE_AGENT) < need)
                        __builtin_amdgcn_s_sleep(8);
                }
                __syncthreads();
                hiF = need;
            }
            f32x4 acc[4][2][4] = {};    // [tt][mt][nt]
            for (int k0 = 0; k0 < H_; k0 += 64) {
#pragma unroll
                for (int tt = 0; tt < 4; ++tt) {
                    int tA = tb + tt; if (tA >= T_) tA = T_ - 1;
                    const unsigned short* Ap = a.Hall + (size_t)tA * B_ * H_;
                    int id = tid;
#pragma unroll
                    for (int it = 0; it < 2; ++it, id += 256) {
                        int row = id >> 3, c8 = (id & 7) * 8;
                        *(ushort8_t*)&As[tt * 4608 + row * 72 + c8] =
                            *(const ushort8_t*)(Ap + (size_t)row * H_ + k0 + c8);
                    }
                }
                {
                    int id2 = tid;
#pragma unroll
                    for (int it = 0; it < 4; ++it, id2 += 256) {
                        int row = id2 >> 3, c8 = (id2 & 7) * 8;
                        int gn = n0 + row;
                        ushort8_t v = {0, 0, 0, 0, 0, 0, 0, 0};
                        if (gn < V_) v = *(const ushort8_t*)(a.Ct + (size_t)gn * H_ + k0 + c8);
                        *(ushort8_t*)&Bs[row * 72 + c8] = v;
                    }
                }
                __syncthreads();
#pragma unroll
                for (int kk = 0; kk < 2; ++kk) {
                    bf16x8 bf[4];
#pragma unroll
                    for (int nt = 0; nt < 4; ++nt)
                        bf[nt] = *(const bf16x8*)&Bs[(nw + nt * 16 + l16) * 72 + kk * 32 + quad * 8];
#pragma unroll
                    for (int tt = 0; tt < 4; ++tt) {
                        bf16x8 af[2];
#pragma unroll
                        for (int mt = 0; mt < 2; ++mt)
                            af[mt] = *(const bf16x8*)&As[tt * 4608 + (mw + mt * 16 + l16) * 72 + kk * 32 + quad * 8];
#pragma unroll
                        for (int mt = 0; mt < 2; ++mt)
#pragma unroll
                            for (int nt = 0; nt < 4; ++nt)
                                acc[tt][mt][nt] = mfma16(af[mt], bf[nt], acc[tt][mt][nt]);
                    }
                }
                __syncthreads();
            }
#pragma unroll
            for (int tt = 0; tt < 4; ++tt) {
                const int t = tb + tt;
                if (t >= T_) continue;
#pragma unroll
                for (int mt = 0; mt < 2; ++mt)
#pragma unroll
                    for (int nt = 0; nt < 4; ++nt) {
                        int col = n0 + nw + nt * 16 + l16;
                        if (col >= V_) continue;
                        float bv = a.Cb[col];
                        int bb = mw + mt * 16 + quad * 4;
#pragma unroll
                        for (int r = 0; r < 4; ++r) {
                            int orow = (bb + r) * T_ + t;
                            a.out[(size_t)orow * V_ + col] = acc[tt][mt][nt][r] + bv;
                        }
                    }
            }
        }
    }
}

extern "C" void kernel_launch(void* const* d_in, const int* in_sizes, int n_in,
                              void* d_out, int out_size, void* d_ws, size_t ws_size,
                              hipStream_t stream) {
    (void)in_sizes; (void)n_in; (void)out_size; (void)ws_size;
    const int* captions = (const int*)d_in[0];
    const float* features = (const float*)d_in[1];
    const float* h0 = (const float*)d_in[2];
    const float* c0 = (const float*)d_in[3];
    const float* Bemb = (const float*)d_in[4];
    const float *iVW[4], *iVb[4], *iSW[4], *iSb[4], *iUW[4], *iUb[4], *iWW[4], *iWb[4];
    for (int g = 0; g < 4; ++g) {
        const int base = 5 + 8 * g;
        iVW[g] = (const float*)d_in[base + 0];
        iVb[g] = (const float*)d_in[base + 1];
        iSW[g] = (const float*)d_in[base + 2];
        iSb[g] = (const float*)d_in[base + 3];
        iUW[g] = (const float*)d_in[base + 4];
        iUb[g] = (const float*)d_in[base + 5];
        iWW[g] = (const float*)d_in[base + 6];
        iWb[g] = (const float*)d_in[base + 7];
    }
    const float* CW = (const float*)d_in[37];
    const float* Cb = (const float*)d_in[38];

    char* w = (char*)d_ws;
    auto alloc = [&](size_t bytes) -> void* {
        void* p = (void*)w;
        w += (bytes + 255) & ~(size_t)255;
        return p;
    };
    int* dbar = (int*)alloc(8192);   // flags + AGGF + PCNT lines
    unsigned short* cH0 = (unsigned short*)alloc((size_t)B_ * H_ * 2);
    unsigned short *wVt[4], *wSt[4], *wUt[4], *wWt[4];
    for (int g = 0; g < 4; ++g) wVt[g] = (unsigned short*)alloc((size_t)FD_ * 320 * 2);
    for (int g = 0; g < 4; ++g) wSt[g] = (unsigned short*)alloc((size_t)FD_ * FD_ * 2);
    for (int g = 0; g < 4; ++g) wUt[g] = (unsigned short*)alloc((size_t)H_ * FD_ * 2);
    for (int g = 0; g < 4; ++g) wWt[g] = (unsigned short*)alloc((size_t)H_ * H_ * 2);
    unsigned short* wCt = (unsigned short*)alloc((size_t)V_ * H_ * 2);
    unsigned short* bufA[4];
    for (int g = 0; g < 4; ++g) bufA[g] = (unsigned short*)alloc((size_t)B_ * T_ * FD_ * 2);
    unsigned short* Hall = (unsigned short*)alloc((size_t)B_ * T_ * H_ * 2);

    // ---- dispatch 1: prep (V/S/U/W transposes + h0 + flags; 3840 blocks)
    {
        PrepA p{};
        for (int g = 0; g < 4; ++g) {
            p.tsrc[g * 3 + 0] = iSW[g]; p.tdst[g * 3 + 0] = wSt[g];
            p.tsrc[g * 3 + 1] = iUW[g]; p.tdst[g * 3 + 1] = wUt[g];
            p.tsrc[g * 3 + 2] = iWW[g]; p.tdst[g * 3 + 2] = wWt[g];
            p.tsrc[12 + g] = iVW[g];    p.tdst[12 + g] = wVt[g];
        }
        p.h0 = h0; p.cH0 = cH0; p.bar = dbar;
        prep_k<<<dim3(3840), 256, 0, stream>>>(p);
    }

    // ---- dispatch 2: fused embed + 3-stage chain (240 WGs, 2/CU)
    {
        ChainA ca{};
        ca.captions = captions; ca.features = features; ca.Bemb = Bemb;
        for (int g = 0; g < 4; ++g) {
            ca.Vt[g] = wVt[g]; ca.Vb[g] = iVb[g];
            ca.St[g] = wSt[g]; ca.Sb[g] = iSb[g];
            ca.Ut[g] = wUt[g]; ca.Ub[g] = iUb[g];
            ca.U[g] = bufA[g];
        }
        chain_k<<<dim3(240), 256, 0, stream>>>(ca);
    }

    // ---- dispatch 3: mega (recurrence + CW transpose + overlapped projection)
    {
        MegaA ma{};
        ma.h0c = cH0;
        for (int g = 0; g < 4; ++g) {
            ma.Wt[g] = wWt[g]; ma.Wb[g] = iWb[g]; ma.U[g] = bufA[g];
        }
        ma.c0 = c0;
        ma.Hall = Hall;
        ma.bar = dbar;
        ma.CW = CW;
        ma.Ct = wCt;
        ma.Cb = Cb;
        ma.out = (float*)d_out;
        mega_k<<<dim3(NR_ + NPW_), 256, 0, stream>>>(ma);
    }
}